// Round 3
// baseline (252.998 us; speedup 1.0000x reference)
//
#include <hip/hip_runtime.h>
#include <math.h>

#define BB 64
#define SS 1024
#define VV 1024
#define DD 512

#define MAP_WORDS  ((size_t)BB * SS * VV)            // 67,108,864
#define STEP_WORDS ((size_t)BB * SS * SS)            // 67,108,864
#define TOT_WORDS  (MAP_WORDS + STEP_WORDS)          // 134,217,728
#define TOT_F4     (TOT_WORDS / 4)                   // 33,554,432
#define MAP_F4     (MAP_WORDS / 4)                   // 16,777,216
#define COPY_BLOCKS 8192
#define F4_PER_BLOCK (TOT_F4 / COPY_BLOCKS)          // 4096 (MAP_F4 % 4096 == 0: no straddle)
#define NGATES (BB * 2)                              // 128

__device__ __forceinline__ float gelu_tanh(float x) {
    const float k = 0.7978845608028654f; // sqrt(2/pi)
    float x3 = x * x * x;
    return 0.5f * x * (1.0f + tanhf(k * (x + 0.044715f * x3)));
}

// ---------------- Kernel A: gate MLPs -> (idx, gate) pairs in ws ----------
// One block per (batch, head). head 0 = map, head 1 = step.
__global__ void __launch_bounds__(256)
gate_kernel(
    const float* __restrict__ evidence,
    const int* __restrict__ marker_id,
    const int* __restrict__ source_idx,
    const int* __restrict__ source_mask,
    const int* __restrict__ target_symbol_idx,
    const int* __restrict__ target_symbol_mask,
    const int* __restrict__ target_value_idx,
    const int* __restrict__ target_value_mask,
    const float* __restrict__ map_W1, const float* __restrict__ map_b1,
    const float* __restrict__ map_W2, const float* __restrict__ map_b2,
    const float* __restrict__ step_W1, const float* __restrict__ step_b1,
    const float* __restrict__ step_W2, const float* __restrict__ step_b2,
    int* __restrict__ ws_idx, float* __restrict__ ws_g)
{
    const int b    = blockIdx.x >> 1;
    const int head = blockIdx.x & 1;
    const float* W1  = head ? step_W1 : map_W1;
    const float* b1  = head ? step_b1 : map_b1;
    const float* W2  = head ? step_W2 : map_W2;
    const float* b2v = head ? step_b2 : map_b2;

    __shared__ float ev[DD];
    __shared__ float wsum[4];

    const int tid = threadIdx.x;
    for (int i = tid; i < DD; i += 256) ev[i] = evidence[b * DD + i];
    __syncthreads();

    float acc = 0.0f;
    #pragma unroll
    for (int jj = 0; jj < DD; jj += 256) {
        const int j = jj + tid;
        float h = b1[j];
        for (int k = 0; k < DD; ++k) {
            h = fmaf(ev[k], W1[k * DD + j], h);
        }
        h = gelu_tanh(h);
        acc = fmaf(h, W2[j], acc);
    }

    #pragma unroll
    for (int off = 32; off > 0; off >>= 1) acc += __shfl_down(acc, off, 64);
    if ((tid & 63) == 0) wsum[tid >> 6] = acc;
    __syncthreads();

    if (tid == 0) {
        float g = wsum[0] + wsum[1] + wsum[2] + wsum[3] + b2v[0];
        g = 1.0f / (1.0f + expf(-g));
        const int m  = marker_id[b];
        const bool sm = source_mask[b] != 0;
        int idx = -1;
        if (head == 0) {
            if (((m == 1) || (m == 2)) && sm && (target_value_mask[b] != 0)) {
                idx = b * (SS * VV) + source_idx[b] * VV + target_value_idx[b];
            }
        } else {
            if ((m == 3) && sm && (target_symbol_mask[b] != 0)) {
                idx = (int)MAP_WORDS + b * (SS * SS) + source_idx[b] * SS
                    + target_symbol_idx[b];
            }
        }
        ws_idx[blockIdx.x] = idx;
        ws_g[blockIdx.x]   = g;
    }
}

// --------------- Kernel B: fused full-BW copy + sparse scatter ------------
// Block-contiguous float4 copy; each block screens the 128 ws entries
// against its range (nm <= 1 by construction) and folds the gate add into
// the owning thread's register before the store.
__global__ void __launch_bounds__(256)
copy_scatter_kernel(
    const float4* __restrict__ map_memory,   // [MAP_F4]
    const float4* __restrict__ step_memory,  // [TOT_F4 - MAP_F4]
    const int* __restrict__ ws_idx,
    const float* __restrict__ ws_g,
    float4* __restrict__ out)                // [TOT_F4]
{
    const long f4_base = (long)blockIdx.x * F4_PER_BLOCK;

    __shared__ int n_match;
    __shared__ int m_f4[8];
    __shared__ int m_lane[8];
    __shared__ float m_g[8];

    if (threadIdx.x == 0) n_match = 0;
    __syncthreads();
    if (threadIdx.x < NGATES) {
        int idx = ws_idx[threadIdx.x];
        if (idx >= 0) {
            long f4 = (long)(idx >> 2);
            long off = f4 - f4_base;
            if (off >= 0 && off < F4_PER_BLOCK) {
                int slot = atomicAdd(&n_match, 1);
                m_f4[slot]   = (int)off;
                m_lane[slot] = idx & 3;
                m_g[slot]    = ws_g[threadIdx.x];
            }
        }
    }
    __syncthreads();
    const int nm = n_match;

    // Each block lies entirely within one half (MAP_F4 % F4_PER_BLOCK == 0).
    const float4* __restrict__ src =
        (f4_base < (long)MAP_F4) ? (map_memory + f4_base)
                                 : (step_memory + (f4_base - (long)MAP_F4));
    float4* __restrict__ dst = out + f4_base;

    for (int i = threadIdx.x; i < F4_PER_BLOCK; i += 256) {
        float4 v = src[i];
        if (nm) {
            for (int e = 0; e < nm; ++e) {
                if (m_f4[e] == i) {
                    const int ln = m_lane[e];
                    const float g = m_g[e];
                    v.x += (ln == 0) ? g : 0.0f;
                    v.y += (ln == 1) ? g : 0.0f;
                    v.z += (ln == 2) ? g : 0.0f;
                    v.w += (ln == 3) ? g : 0.0f;
                }
            }
        }
        dst[i] = v;
    }
}

extern "C" void kernel_launch(void* const* d_in, const int* in_sizes, int n_in,
                              void* d_out, int out_size, void* d_ws, size_t ws_size,
                              hipStream_t stream) {
    const float* map_memory  = (const float*)d_in[0];
    const float* step_memory = (const float*)d_in[1];
    const float* evidence    = (const float*)d_in[2];
    const int* marker_id     = (const int*)d_in[3];
    const int* source_idx    = (const int*)d_in[4];
    const int* source_mask        = (const int*)d_in[5];
    const int* target_symbol_idx  = (const int*)d_in[6];
    const int* target_symbol_mask = (const int*)d_in[7];
    const int* target_value_idx   = (const int*)d_in[8];
    const int* target_value_mask  = (const int*)d_in[9];
    const float* map_W1  = (const float*)d_in[10];
    const float* map_b1  = (const float*)d_in[11];
    const float* map_W2  = (const float*)d_in[12];
    const float* map_b2  = (const float*)d_in[13];
    const float* step_W1 = (const float*)d_in[14];
    const float* step_b1 = (const float*)d_in[15];
    const float* step_W2 = (const float*)d_in[16];
    const float* step_b2 = (const float*)d_in[17];

    char* ws = (char*)d_ws;
    int*   ws_idx = (int*)ws;
    float* ws_g   = (float*)(ws + NGATES * sizeof(int));

    // A: compute gates + target indices into workspace.
    gate_kernel<<<dim3(NGATES), dim3(256), 0, stream>>>(
        evidence, marker_id, source_idx, source_mask,
        target_symbol_idx, target_symbol_mask,
        target_value_idx, target_value_mask,
        map_W1, map_b1, map_W2, map_b2,
        step_W1, step_b1, step_W2, step_b2,
        ws_idx, ws_g);

    // B: single full-bandwidth pass-through with fused scatter-add.
    copy_scatter_kernel<<<dim3(COPY_BLOCKS), dim3(256), 0, stream>>>(
        (const float4*)map_memory, (const float4*)step_memory,
        ws_idx, ws_g, (float4*)d_out);
}

// Round 5
// 241.309 us; speedup vs baseline: 1.0484x; 1.0484x over previous
//
#include <hip/hip_runtime.h>
#include <math.h>

#define BB 64
#define SS 1024
#define VV 1024
#define DD 512

#define MAP_WORDS  ((size_t)BB * SS * VV)            // 67,108,864
#define STEP_WORDS ((size_t)BB * SS * SS)            // 67,108,864
#define TOT_WORDS  (MAP_WORDS + STEP_WORDS)          // 134,217,728
#define TOT_F4     (TOT_WORDS / 4)                   // 33,554,432
#define MAP_F4     (MAP_WORDS / 4)                   // 16,777,216

#define COPY_BLOCKS 4096
#define COPY_THREADS 256

// Native clang vector type — required by __builtin_nontemporal_*.
typedef float f32x4 __attribute__((ext_vector_type(4)));

__device__ __forceinline__ float gelu_tanh(float x) {
    const float k = 0.7978845608028654f; // sqrt(2/pi)
    float x3 = x * x * x;
    return 0.5f * x * (1.0f + tanhf(k * (x + 0.044715f * x3)));
}

// ---------------- Kernel 1: pure streaming copy (no scatter logic) --------
// Grid-stride f32x4 with non-temporal load/store: avoid L2 write-allocate
// pollution while streaming 1.07 GB through a 32 MB L2.
__global__ void __launch_bounds__(COPY_THREADS)
copy_kernel(const f32x4* __restrict__ map_memory,
            const f32x4* __restrict__ step_memory,
            f32x4* __restrict__ out)
{
    const size_t stride = (size_t)COPY_BLOCKS * COPY_THREADS;
    size_t i = (size_t)blockIdx.x * COPY_THREADS + threadIdx.x;
    // First half: map_memory -> out[0 : MAP_F4)
    for (; i < MAP_F4; i += stride) {
        f32x4 v = __builtin_nontemporal_load(&map_memory[i]);
        __builtin_nontemporal_store(v, &out[i]);
    }
    // Second half: step_memory -> out[MAP_F4 : TOT_F4)
    for (i = (size_t)blockIdx.x * COPY_THREADS + threadIdx.x;
         i < (TOT_F4 - MAP_F4); i += stride) {
        f32x4 v = __builtin_nontemporal_load(&step_memory[i]);
        __builtin_nontemporal_store(v, &out[MAP_F4 + i]);
    }
}

// ---------------- Kernel 2: gate MLPs + direct RMW scatter into out -------
// One block per (batch, head). Runs AFTER the copy; per-batch targets are
// unique locations, so plain read-modify-write is race-free.
__global__ void __launch_bounds__(256)
gate_scatter_kernel(
    const float* __restrict__ evidence,
    const int* __restrict__ marker_id,
    const int* __restrict__ source_idx,
    const int* __restrict__ source_mask,
    const int* __restrict__ target_symbol_idx,
    const int* __restrict__ target_symbol_mask,
    const int* __restrict__ target_value_idx,
    const int* __restrict__ target_value_mask,
    const float* __restrict__ map_W1, const float* __restrict__ map_b1,
    const float* __restrict__ map_W2, const float* __restrict__ map_b2,
    const float* __restrict__ step_W1, const float* __restrict__ step_b1,
    const float* __restrict__ step_W2, const float* __restrict__ step_b2,
    float* __restrict__ out)
{
    const int b    = blockIdx.x >> 1;
    const int head = blockIdx.x & 1;
    const float* W1  = head ? step_W1 : map_W1;
    const float* b1  = head ? step_b1 : map_b1;
    const float* W2  = head ? step_W2 : map_W2;
    const float* b2v = head ? step_b2 : map_b2;

    __shared__ float ev[DD];
    __shared__ float wsum[4];

    const int tid = threadIdx.x;
    for (int i = tid; i < DD; i += 256) ev[i] = evidence[b * DD + i];
    __syncthreads();

    float acc = 0.0f;
    #pragma unroll
    for (int jj = 0; jj < DD; jj += 256) {
        const int j = jj + tid;
        float h = b1[j];
        for (int k = 0; k < DD; ++k) {
            h = fmaf(ev[k], W1[k * DD + j], h);
        }
        h = gelu_tanh(h);
        acc = fmaf(h, W2[j], acc);
    }

    #pragma unroll
    for (int off = 32; off > 0; off >>= 1) acc += __shfl_down(acc, off, 64);
    if ((tid & 63) == 0) wsum[tid >> 6] = acc;
    __syncthreads();

    if (tid == 0) {
        float g = wsum[0] + wsum[1] + wsum[2] + wsum[3] + b2v[0];
        g = 1.0f / (1.0f + expf(-g));
        const int m  = marker_id[b];
        const bool sm = source_mask[b] != 0;
        if (head == 0) {
            if (((m == 1) || (m == 2)) && sm && (target_value_mask[b] != 0)) {
                size_t idx = (size_t)b * SS * VV + (size_t)source_idx[b] * VV
                           + (size_t)target_value_idx[b];
                out[idx] += g;
            }
        } else {
            if ((m == 3) && sm && (target_symbol_mask[b] != 0)) {
                size_t idx = MAP_WORDS + (size_t)b * SS * SS
                           + (size_t)source_idx[b] * SS + (size_t)target_symbol_idx[b];
                out[idx] += g;
            }
        }
    }
}

extern "C" void kernel_launch(void* const* d_in, const int* in_sizes, int n_in,
                              void* d_out, int out_size, void* d_ws, size_t ws_size,
                              hipStream_t stream) {
    const float* map_memory  = (const float*)d_in[0];
    const float* step_memory = (const float*)d_in[1];
    const float* evidence    = (const float*)d_in[2];
    const int* marker_id     = (const int*)d_in[3];
    const int* source_idx    = (const int*)d_in[4];
    const int* source_mask        = (const int*)d_in[5];
    const int* target_symbol_idx  = (const int*)d_in[6];
    const int* target_symbol_mask = (const int*)d_in[7];
    const int* target_value_idx   = (const int*)d_in[8];
    const int* target_value_mask  = (const int*)d_in[9];
    const float* map_W1  = (const float*)d_in[10];
    const float* map_b1  = (const float*)d_in[11];
    const float* map_W2  = (const float*)d_in[12];
    const float* map_b2  = (const float*)d_in[13];
    const float* step_W1 = (const float*)d_in[14];
    const float* step_b1 = (const float*)d_in[15];
    const float* step_W2 = (const float*)d_in[16];
    const float* step_b2 = (const float*)d_in[17];

    float* out = (float*)d_out;

    // 1) Full-bandwidth pass-through copy.
    copy_kernel<<<dim3(COPY_BLOCKS), dim3(COPY_THREADS), 0, stream>>>(
        (const f32x4*)map_memory, (const f32x4*)step_memory, (f32x4*)out);

    // 2) Gate MLPs + masked single-element RMW scatter (after the copy).
    gate_scatter_kernel<<<dim3(BB * 2), dim3(256), 0, stream>>>(
        evidence, marker_id, source_idx, source_mask,
        target_symbol_idx, target_symbol_mask,
        target_value_idx, target_value_mask,
        map_W1, map_b1, map_W2, map_b2,
        step_W1, step_b1, step_W2, step_b2,
        out);
}